// Round 11
// baseline (115.010 us; speedup 1.0000x reference)
//
#include <hip/hip_runtime.h>

// QuadraticConv2D: B=8 H=56 W=56 C=64 O=128, 55 quadratic pairs over (ones + 9 shifts)
// GEMM M=25088 pixels, K=55x64, N=128.
// R11 = R10 (fragment-major B, asm-pinned pipeline) + 2 rows/block, 512 threads:
//   - 8 waves = (row, nq): row-twin waves share the B stream (L1 hits) -> chip B
//     traffic 394->197 MB; MFMA pipe becomes the single dominant per-CU cost.
//   - 2 waves/SIMD everywhere: vmcnt stalls in one wave are covered by its mate.

#define CB 8
#define CH 56
#define CW 56
#define CC 64
#define CO 128
#define RS 72   // row stride in f16 (144 B)

typedef __attribute__((ext_vector_type(8))) _Float16 v8hf;  // MFMA A/B frag (4 VGPRs)
typedef __attribute__((ext_vector_type(16))) float f16f;    // 32x32 accumulator
typedef __attribute__((address_space(3))) const _Float16 lds_cf16;

// pair tables: p-th pair (i,j), i=0..9, j=i..9 (reference order)
__device__ constexpr int PII[55] = {0,0,0,0,0,0,0,0,0,0, 1,1,1,1,1,1,1,1,1, 2,2,2,2,2,2,2,2,
                                    3,3,3,3,3,3,3, 4,4,4,4,4,4, 5,5,5,5,5, 6,6,6,6, 7,7,7, 8,8, 9};
__device__ constexpr int PJJ[55] = {0,1,2,3,4,5,6,7,8,9, 1,2,3,4,5,6,7,8,9, 2,3,4,5,6,7,8,9,
                                    3,4,5,6,7,8,9, 4,5,6,7,8,9, 5,6,7,8,9, 6,7,8,9, 7,8,9, 8,9, 9};

// ---- prep: kernel [55][64][128] f32 -> BtF [55][4 ks][4 nq][64 lane][8] f16
// (exact per-wave MFMA B-fragment order: n = nq*32+(lane&31), k = ks*16+(lane>>5)*8+e)
__global__ __launch_bounds__(256) void prep_kernel(const float* __restrict__ K,
                                                   _Float16* __restrict__ BtF) {
  __shared__ float tile[CC * CO];
  const int p = blockIdx.x;
  const int t = threadIdx.x;
  const float* src = K + (size_t)p * CC * CO;
#pragma unroll
  for (int e = 0; e < 8; ++e) {
    const int idx = t * 4 + e * 1024;
    *(float4*)&tile[idx] = *(const float4*)&src[idx];
  }
  __syncthreads();
#pragma unroll
  for (int e4 = 0; e4 < 4; ++e4) {
    const int idx = e4 * 256 + t;          // 0..1023 = ((ks*4 + nq)*64 + lane)
    const int lane = idx & 63;
    const int nqq = (idx >> 6) & 3;
    const int ksq = idx >> 8;
    const int n = nqq * 32 + (lane & 31);
    const int kb = ksq * 16 + (lane >> 5) * 8;
    _Float16 ov[8];
#pragma unroll
    for (int e = 0; e < 8; ++e)
      ov[e] = (_Float16)tile[(kb + e) * CO + n];
    *(v8hf*)(BtF + ((size_t)p * 1024 + idx) * 8) = *(const v8hf*)ov;
  }
}

// ---- main: one block per (b, row-pair). 512 threads = 8 waves: wave = (rw, nq).
// Wave computes 2 m-tiles of row h0+rw: cols 0..31 and 32..55(+pad).
__global__ __launch_bounds__(512, 1) void quad_kernel(const float* __restrict__ in,
                                                      const _Float16* __restrict__ BtF,
                                                      float* __restrict__ out) {
  __shared__ _Float16 rowsH[4][64][RS];  // rows h0-1..h0+2 (f16), col = w+1 halo, 36.9 KB

  const int t = threadIdx.x;
  const int b = blockIdx.x / (CH / 2);
  const int h0 = (blockIdx.x % (CH / 2)) * 2;

  // stage 4 input rows into LDS (f16) with zero halo (w=-1, w>=56) / zero OOB rows
  {
    const int tt = t & 255;
    const int r0 = t >> 8;           // 0 or 1
    const int col = tt >> 2;         // 0..63
    const int cg = (tt & 3) * 16;    // 16-channel group
    const int w = col - 1;
#pragma unroll
    for (int rx = 0; rx < 2; ++rx) {
      const int r = r0 + rx * 2;     // covers rows 0..3
      const int hh = h0 + r - 1;
      const bool valid = (hh >= 0) && (hh < CH) && (w >= 0) && (w < CW);
      float4 v0 = make_float4(0.f, 0.f, 0.f, 0.f), v1 = v0, v2 = v0, v3 = v0;
      if (valid) {
        const float* s = in + (((size_t)(b * CH + hh)) * CW + w) * CC + cg;
        v0 = *(const float4*)(s);
        v1 = *(const float4*)(s + 4);
        v2 = *(const float4*)(s + 8);
        v3 = *(const float4*)(s + 12);
      }
      _Float16 pv[16];
      pv[0] = (_Float16)v0.x;  pv[1] = (_Float16)v0.y;  pv[2] = (_Float16)v0.z;  pv[3] = (_Float16)v0.w;
      pv[4] = (_Float16)v1.x;  pv[5] = (_Float16)v1.y;  pv[6] = (_Float16)v1.z;  pv[7] = (_Float16)v1.w;
      pv[8] = (_Float16)v2.x;  pv[9] = (_Float16)v2.y;  pv[10] = (_Float16)v2.z; pv[11] = (_Float16)v2.w;
      pv[12] = (_Float16)v3.x; pv[13] = (_Float16)v3.y; pv[14] = (_Float16)v3.z; pv[15] = (_Float16)v3.w;
      _Float16* d = &rowsH[r][col][cg];
      *(v8hf*)(d) = *(const v8hf*)&pv[0];
      *(v8hf*)(d + 8) = *(const v8hf*)&pv[8];
    }
  }

  const int lane = t & 63;
  const int wid = t >> 6;       // 0..7
  const int rw = wid >> 2;      // row within pair: 0 or 1
  const int nq = wid & 3;       // N-quarter 0..3
  const int ml = lane & 31;     // 32x32 MFMA: m (A) / n (B) lane index
  const int hk = lane >> 5;     // k-half selector
  const int h8 = hk * 8;

  f16f acc0, acc1;
#pragma unroll
  for (int r = 0; r < 16; ++r) { acc0[r] = 0.f; acc1[r] = 0.f; }

  // wave's B base: BtF + ((p*4 + ks)*4 + nq)*512 + lane*8 (coalesced 1 KB per load;
  // rw-twin waves issue identical addresses -> L1 hits for the second)
  const _Float16* Bw = BtF + (size_t)(nq * 64 + lane) * 8;
  const v8hf vone = {1, 1, 1, 1, 1, 1, 1, 1};

  // AS3 base pointer for asm ds_read (addrspacecast, 32-bit operand)
  lds_cf16* lds3 = (lds_cf16*)&rowsH[0][0][0];

  // prefetch ring, depth 11 (asm loads; issue order pinned by volatile)
  // flat step s = ks*55 + p; element offset = p*8192 + ks*2048
  v8hf ring[11];
#pragma unroll
  for (int p = 0; p < 11; ++p) {
    const _Float16* ba = Bw + (size_t)p * 8192;
    asm volatile("global_load_dwordx4 %0, %1, off" : "=v"(ring[p]) : "v"(ba));
  }

  __syncthreads();  // rowsH ready; no further barriers

#pragma unroll 1
  for (int ks = 0; ks < 4; ++ks) {  // K=64 channels in 4 steps of 16
    const int koff = ks * 16 + h8;
    // shift vectors for the 2 m-tiles: asm ds_read_b128 -> pinned in VGPRs
    v8hf s0[9], s1[9];
#pragma unroll
    for (int tt = 0; tt < 9; ++tt) {
      const int rr = rw + tt / 3, sc = tt % 3;
      const int c0 = ml + sc;                         // tile 0: max 33, in range
      int c1 = 32 + ml + sc; c1 = c1 > 63 ? 63 : c1;  // tile 1: clamp (cols>=57 staged zero)
      lds_cf16* p0 = lds3 + (rr * 64 + c0) * RS + koff;
      lds_cf16* p1 = lds3 + (rr * 64 + c1) * RS + koff;
      asm volatile("ds_read_b128 %0, %1" : "=v"(s0[tt]) : "v"(p0));
      asm volatile("ds_read_b128 %0, %1" : "=v"(s1[tt]) : "v"(p1));
    }
    // one wait for all 18; ties the values so uses can't float above it
    asm volatile("s_waitcnt lgkmcnt(0)"
                 : "+v"(s0[0]), "+v"(s0[1]), "+v"(s0[2]), "+v"(s0[3]), "+v"(s0[4]),
                   "+v"(s0[5]), "+v"(s0[6]), "+v"(s0[7]), "+v"(s0[8]),
                   "+v"(s1[0]), "+v"(s1[1]), "+v"(s1[2]), "+v"(s1[3]), "+v"(s1[4]),
                   "+v"(s1[5]), "+v"(s1[6]), "+v"(s1[7]), "+v"(s1[8]));

    const int ksn = (ks < 3) ? ks + 1 : 3;  // tail prefetch clamp (redundant, harmless)
#pragma unroll
    for (int p = 0; p < 55; ++p) {
      // wait until the slot's load (issued 11 steps ago) has landed; 10 newer in flight
      asm volatile("s_waitcnt vmcnt(10)" : "+v"(ring[p % 11]));
      const v8hf bb = ring[p % 11];
      // refill the slot with flat step s+11 (p constant after unroll -> address folds)
      {
        const int p2 = (p < 44) ? p + 11 : p - 44;
        const int ks2 = (p < 44) ? ks : ksn;
        const _Float16* ba = Bw + (size_t)p2 * 8192 + ks2 * 2048;
        asm volatile("global_load_dwordx4 %0, %1, off" : "=v"(ring[p % 11]) : "v"(ba));
      }
      const int pi = PII[p], pj = PJJ[p];
      v8hf a0, a1;
      if (pi == 0) {
        if (pj == 0) { a0 = vone; a1 = vone; }
        else { a0 = s0[pj - 1]; a1 = s1[pj - 1]; }
      } else {
        a0 = s0[pi - 1] * s0[pj - 1];
        a1 = s1[pi - 1] * s1[pj - 1];
      }
      acc0 = __builtin_amdgcn_mfma_f32_32x32x16_f16(a0, bb, acc0, 0, 0, 0);
      acc1 = __builtin_amdgcn_mfma_f32_32x32x16_f16(a1, bb, acc1, 0, 0, 0);
    }
  }
  // drain the 11 stray tail prefetches before the epilogue
  asm volatile("s_waitcnt vmcnt(0)");

  // epilogue: 32x32 C/D layout col=lane&31 (n), row=(reg&3)+8*(reg>>2)+4*(lane>>5) (m)
  float* ob = out + ((size_t)(b * CH + h0 + rw) * CW) * CO + nq * 32 + ml;
#pragma unroll
  for (int r = 0; r < 16; ++r) {  // tile 0: w = 0..31, all real
    const int wp = (r & 3) + 8 * (r >> 2) + 4 * hk;
    ob[(size_t)wp * CO] = acc0[r];
  }
#pragma unroll
  for (int r = 0; r < 12; ++r) {  // tile 1: w = 32..55; regs 12..15 are w>=56 pad
    const int wp = 32 + (r & 3) + 8 * (r >> 2) + 4 * hk;
    ob[(size_t)wp * CO] = acc1[r];
  }
}

extern "C" void kernel_launch(void* const* d_in, const int* in_sizes, int n_in,
                              void* d_out, int out_size, void* d_ws, size_t ws_size,
                              hipStream_t stream) {
  const float* in = (const float*)d_in[0];      // [8,56,56,64] f32
  const float* K = (const float*)d_in[1];       // [55,64,128] f32
  float* out = (float*)d_out;                   // [8,56,56,128] f32
  _Float16* BtF = (_Float16*)d_ws;              // [55][4][4][64][8] f16 = 901,120 B
  (void)in_sizes; (void)n_in; (void)out_size; (void)ws_size;

  prep_kernel<<<55, 256, 0, stream>>>(K, BtF);
  quad_kernel<<<CB * (CH / 2), 512, 0, stream>>>(in, BtF, out);
}

// Round 12
// 86.180 us; speedup vs baseline: 1.3345x; 1.3345x over previous
//
#include <hip/hip_runtime.h>

// QuadraticConv2D: B=8 H=56 W=56 C=64 O=128, 55 quadratic pairs over (ones + 9 shifts)
// GEMM M=25088 pixels, K=55x64, N=128.
// R12 = R10 (fragment-major B, asm-pinned ring-11, 256thr/(256,1)) with M=128/wave:
//   wave = nq, covering 4 m-tiles (2 rows x 2 col-halves). The 2-row window shares
//   shift vectors: only 24 distinct (4 rows x 3 dx x 2 cols) = 96 VGPR. Halves
//   per-CU B return-path bytes (900 KB) and outstanding lines vs R10; MFMA becomes
//   the dominant per-CU pipe (~11.8 us). 224 blocks, 1/CU.

#define CB 8
#define CH 56
#define CW 56
#define CC 64
#define CO 128
#define RS 72   // row stride in f16 (144 B)

typedef __attribute__((ext_vector_type(8))) _Float16 v8hf;  // MFMA A/B frag (4 VGPRs)
typedef __attribute__((ext_vector_type(16))) float f16f;    // 32x32 accumulator
typedef __attribute__((address_space(3))) const _Float16 lds_cf16;

// pair tables: p-th pair (i,j), i=0..9, j=i..9 (reference order)
__device__ constexpr int PII[55] = {0,0,0,0,0,0,0,0,0,0, 1,1,1,1,1,1,1,1,1, 2,2,2,2,2,2,2,2,
                                    3,3,3,3,3,3,3, 4,4,4,4,4,4, 5,5,5,5,5, 6,6,6,6, 7,7,7, 8,8, 9};
__device__ constexpr int PJJ[55] = {0,1,2,3,4,5,6,7,8,9, 1,2,3,4,5,6,7,8,9, 2,3,4,5,6,7,8,9,
                                    3,4,5,6,7,8,9, 4,5,6,7,8,9, 5,6,7,8,9, 6,7,8,9, 7,8,9, 8,9, 9};

// ---- prep: kernel [55][64][128] f32 -> BtF [55][4 ks][4 nq][64 lane][8] f16
// (exact per-wave MFMA B-fragment order: n = nq*32+(lane&31), k = ks*16+(lane>>5)*8+e)
__global__ __launch_bounds__(256) void prep_kernel(const float* __restrict__ K,
                                                   _Float16* __restrict__ BtF) {
  __shared__ float tile[CC * CO];
  const int p = blockIdx.x;
  const int t = threadIdx.x;
  const float* src = K + (size_t)p * CC * CO;
#pragma unroll
  for (int e = 0; e < 8; ++e) {
    const int idx = t * 4 + e * 1024;
    *(float4*)&tile[idx] = *(const float4*)&src[idx];
  }
  __syncthreads();
#pragma unroll
  for (int e4 = 0; e4 < 4; ++e4) {
    const int idx = e4 * 256 + t;          // 0..1023 = ((ks*4 + nq)*64 + lane)
    const int lane = idx & 63;
    const int nqq = (idx >> 6) & 3;
    const int ksq = idx >> 8;
    const int n = nqq * 32 + (lane & 31);
    const int kb = ksq * 16 + (lane >> 5) * 8;
    _Float16 ov[8];
#pragma unroll
    for (int e = 0; e < 8; ++e)
      ov[e] = (_Float16)tile[(kb + e) * CO + n];
    *(v8hf*)(BtF + ((size_t)p * 1024 + idx) * 8) = *(const v8hf*)ov;
  }
}

// ---- main: one block per (b, row-pair). 256 threads = 4 waves, wave = N-quarter.
// Wave computes 4 m-tiles: rows h0,h0+1 x cols {0..31, 32..63(pad>=56)}.
__global__ __launch_bounds__(256, 1) void quad_kernel(const float* __restrict__ in,
                                                      const _Float16* __restrict__ BtF,
                                                      float* __restrict__ out) {
  __shared__ _Float16 rowsH[4][64][RS];  // rows h0-1..h0+2 (f16), col = w+1 halo, 36.9 KB

  const int t = threadIdx.x;
  const int b = blockIdx.x / (CH / 2);
  const int h0 = (blockIdx.x % (CH / 2)) * 2;

  // stage 4 input rows into LDS (f16) with zero halo (w=-1, w>=56) / zero OOB rows
  {
    const int col = t >> 2;          // 0..63
    const int cg = (t & 3) * 16;     // 16-channel group
    const int w = col - 1;
#pragma unroll
    for (int r = 0; r < 4; ++r) {
      const int hh = h0 + r - 1;
      const bool valid = (hh >= 0) && (hh < CH) && (w >= 0) && (w < CW);
      float4 v0 = make_float4(0.f, 0.f, 0.f, 0.f), v1 = v0, v2 = v0, v3 = v0;
      if (valid) {
        const float* s = in + (((size_t)(b * CH + hh)) * CW + w) * CC + cg;
        v0 = *(const float4*)(s);
        v1 = *(const float4*)(s + 4);
        v2 = *(const float4*)(s + 8);
        v3 = *(const float4*)(s + 12);
      }
      _Float16 pv[16];
      pv[0] = (_Float16)v0.x;  pv[1] = (_Float16)v0.y;  pv[2] = (_Float16)v0.z;  pv[3] = (_Float16)v0.w;
      pv[4] = (_Float16)v1.x;  pv[5] = (_Float16)v1.y;  pv[6] = (_Float16)v1.z;  pv[7] = (_Float16)v1.w;
      pv[8] = (_Float16)v2.x;  pv[9] = (_Float16)v2.y;  pv[10] = (_Float16)v2.z; pv[11] = (_Float16)v2.w;
      pv[12] = (_Float16)v3.x; pv[13] = (_Float16)v3.y; pv[14] = (_Float16)v3.z; pv[15] = (_Float16)v3.w;
      _Float16* d = &rowsH[r][col][cg];
      *(v8hf*)(d) = *(const v8hf*)&pv[0];
      *(v8hf*)(d + 8) = *(const v8hf*)&pv[8];
    }
  }

  const int lane = t & 63;
  const int nq = t >> 6;        // N-quarter 0..3
  const int ml = lane & 31;     // 32x32 MFMA: m (A) / n (B) lane index
  const int hk = lane >> 5;     // k-half selector
  const int h8 = hk * 8;

  f16f acc00, acc01, acc10, acc11;   // [row r][col-tile c]
#pragma unroll
  for (int r = 0; r < 16; ++r) { acc00[r] = 0.f; acc01[r] = 0.f; acc10[r] = 0.f; acc11[r] = 0.f; }

  // wave's B base: BtF + ((p*4 + ks)*4 + nq)*512 + lane*8 (coalesced 1 KB per load)
  const _Float16* Bw = BtF + (size_t)(nq * 64 + lane) * 8;
  const v8hf vone = {1, 1, 1, 1, 1, 1, 1, 1};

  // AS3 base pointer for asm ds_read (addrspacecast, 32-bit operand)
  lds_cf16* lds3 = (lds_cf16*)&rowsH[0][0][0];

  // prefetch ring, depth 11 (asm loads; issue order pinned by volatile)
  // flat step s = ks*55 + p; element offset = p*8192 + ks*2048
  v8hf ring[11];
#pragma unroll
  for (int p = 0; p < 11; ++p) {
    const _Float16* ba = Bw + (size_t)p * 8192;
    asm volatile("global_load_dwordx4 %0, %1, off" : "=v"(ring[p]) : "v"(ba));
  }

  __syncthreads();  // rowsH ready; no further barriers

#pragma unroll 1
  for (int ks = 0; ks < 4; ++ks) {  // K=64 channels in 4 steps of 16
    const int koff = ks * 16 + h8;
    // 24 shared shift vectors: sv{c}[rr*3+dx] = rowsH[rr][c*32+ml+dx][koff]
    v8hf sv0[12], sv1[12];
#pragma unroll
    for (int rr = 0; rr < 4; ++rr)
#pragma unroll
      for (int dx = 0; dx < 3; ++dx) {
        const int c0 = ml + dx;                         // max 33, in range
        int c1 = 32 + ml + dx; c1 = c1 > 63 ? 63 : c1;  // clamp (cols>=57 staged zero)
        lds_cf16* p0 = lds3 + (rr * 64 + c0) * RS + koff;
        lds_cf16* p1 = lds3 + (rr * 64 + c1) * RS + koff;
        asm volatile("ds_read_b128 %0, %1" : "=v"(sv0[rr * 3 + dx]) : "v"(p0));
        asm volatile("ds_read_b128 %0, %1" : "=v"(sv1[rr * 3 + dx]) : "v"(p1));
      }
    // one wait for all 24; ties the values so uses can't float above it
    asm volatile("s_waitcnt lgkmcnt(0)"
                 : "+v"(sv0[0]), "+v"(sv0[1]), "+v"(sv0[2]), "+v"(sv0[3]),
                   "+v"(sv0[4]), "+v"(sv0[5]), "+v"(sv0[6]), "+v"(sv0[7]),
                   "+v"(sv0[8]), "+v"(sv0[9]), "+v"(sv0[10]), "+v"(sv0[11]),
                   "+v"(sv1[0]), "+v"(sv1[1]), "+v"(sv1[2]), "+v"(sv1[3]),
                   "+v"(sv1[4]), "+v"(sv1[5]), "+v"(sv1[6]), "+v"(sv1[7]),
                   "+v"(sv1[8]), "+v"(sv1[9]), "+v"(sv1[10]), "+v"(sv1[11]));

    const int ksn = (ks < 3) ? ks + 1 : 3;  // tail prefetch clamp (redundant, harmless)
#pragma unroll
    for (int p = 0; p < 55; ++p) {
      // wait until the slot's load (issued 11 steps ago) has landed; 10 newer in flight
      asm volatile("s_waitcnt vmcnt(10)" : "+v"(ring[p % 11]));
      const v8hf bb = ring[p % 11];
      // refill the slot with flat step s+11 (p constant after unroll -> address folds)
      {
        const int p2 = (p < 44) ? p + 11 : p - 44;
        const int ks2 = (p < 44) ? ks : ksn;
        const _Float16* ba = Bw + (size_t)p2 * 8192 + ks2 * 2048;
        asm volatile("global_load_dwordx4 %0, %1, off" : "=v"(ring[p % 11]) : "v"(ba));
      }
      const int pi = PII[p], pj = PJJ[p];
      v8hf a00, a01, a10, a11;
      if (pi == 0) {
        if (pj == 0) { a00 = vone; a01 = vone; a10 = vone; a11 = vone; }
        else {
          const int dy = (pj - 1) / 3, dx = (pj - 1) % 3;
          a00 = sv0[dy * 3 + dx];        a01 = sv1[dy * 3 + dx];
          a10 = sv0[(dy + 1) * 3 + dx];  a11 = sv1[(dy + 1) * 3 + dx];
        }
      } else {
        const int dyi = (pi - 1) / 3, dxi = (pi - 1) % 3;
        const int dyj = (pj - 1) / 3, dxj = (pj - 1) % 3;
        a00 = sv0[dyi * 3 + dxi] * sv0[dyj * 3 + dxj];
        a01 = sv1[dyi * 3 + dxi] * sv1[dyj * 3 + dxj];
        a10 = sv0[(dyi + 1) * 3 + dxi] * sv0[(dyj + 1) * 3 + dxj];
        a11 = sv1[(dyi + 1) * 3 + dxi] * sv1[(dyj + 1) * 3 + dxj];
      }
      acc00 = __builtin_amdgcn_mfma_f32_32x32x16_f16(a00, bb, acc00, 0, 0, 0);
      acc01 = __builtin_amdgcn_mfma_f32_32x32x16_f16(a01, bb, acc01, 0, 0, 0);
      acc10 = __builtin_amdgcn_mfma_f32_32x32x16_f16(a10, bb, acc10, 0, 0, 0);
      acc11 = __builtin_amdgcn_mfma_f32_32x32x16_f16(a11, bb, acc11, 0, 0, 0);
    }
  }
  // drain the 11 stray tail prefetches before the epilogue
  asm volatile("s_waitcnt vmcnt(0)");

  // epilogue: 32x32 C/D layout col=lane&31 (n), row=(reg&3)+8*(reg>>2)+4*(lane>>5) (m)
#pragma unroll
  for (int rw = 0; rw < 2; ++rw) {
    float* ob = out + ((size_t)(b * CH + h0 + rw) * CW) * CO + nq * 32 + ml;
    const f16f accc0 = rw ? acc10 : acc00;
    const f16f accc1 = rw ? acc11 : acc01;
#pragma unroll
    for (int r = 0; r < 16; ++r) {  // col-tile 0: w = 0..31, all real
      const int wp = (r & 3) + 8 * (r >> 2) + 4 * hk;
      ob[(size_t)wp * CO] = accc0[r];
    }
#pragma unroll
    for (int r = 0; r < 12; ++r) {  // col-tile 1: w = 32..55; regs 12..15 are w>=56 pad
      const int wp = 32 + (r & 3) + 8 * (r >> 2) + 4 * hk;
      ob[(size_t)wp * CO] = accc1[r];
    }
  }
}

extern "C" void kernel_launch(void* const* d_in, const int* in_sizes, int n_in,
                              void* d_out, int out_size, void* d_ws, size_t ws_size,
                              hipStream_t stream) {
  const float* in = (const float*)d_in[0];      // [8,56,56,64] f32
  const float* K = (const float*)d_in[1];       // [55,64,128] f32
  float* out = (float*)d_out;                   // [8,56,56,128] f32
  _Float16* BtF = (_Float16*)d_ws;              // [55][4][4][64][8] f16 = 901,120 B
  (void)in_sizes; (void)n_in; (void)out_size; (void)ws_size;

  prep_kernel<<<55, 256, 0, stream>>>(K, BtF);
  quad_kernel<<<CB * (CH / 2), 256, 0, stream>>>(in, BtF, out);
}